// Round 1
// baseline (262.138 us; speedup 1.0000x reference)
//
#include <hip/hip_runtime.h>
#include <stdint.h>

typedef _Float16 f16x8 __attribute__((ext_vector_type(8)));
typedef float f32x4 __attribute__((ext_vector_type(4)));

__device__ __forceinline__ unsigned short f2h(float f) {
  _Float16 h = (_Float16)f;
  return __builtin_bit_cast(unsigned short, h);
}

#if __has_builtin(__builtin_amdgcn_global_load_lds)
#define HAVE_GLL 1
__device__ __forceinline__ void gload_lds16(const void* g, void* l) {
  auto gp = reinterpret_cast<const __attribute__((address_space(1))) void*>(
      reinterpret_cast<uintptr_t>(g));
  auto lp = reinterpret_cast<__attribute__((address_space(3))) void*>(
      reinterpret_cast<uintptr_t>(l));
  __builtin_amdgcn_global_load_lds(gp, lp, 16, 0, 0);
}
#else
#define HAVE_GLL 0
#endif

#if HAVE_GLL
#define WAITV(n) asm volatile("s_waitcnt vmcnt(" #n ")" ::: "memory")
#else
// fallback staging uses ds_write: drain LDS ops before barriers instead
#define WAITV(n) asm volatile("s_waitcnt lgkmcnt(0)" ::: "memory")
#endif
#define WAITL0                                        \
  asm volatile("s_waitcnt lgkmcnt(0)" ::: "memory"); \
  __builtin_amdgcn_sched_barrier(0)
#define BAR __builtin_amdgcn_s_barrier()

// ==================== 256x256 8-phase core (R12) ====================
// C[M,N] = A[M,K] * B[N,K]^T, fp16 in, fp16 out. 512 threads = 8 waves (2M x 4N),
// per-wave 128x64 output, mfma 16x16x32 f16, BK=64 split into two 32-wide k-halves.
// LDS 128 KiB: per operand [buf2][kh2][256 rows][32 k] fp16 (8192 ushort planes).
// Swizzle: 16B slot = kc ^ ((row>>1)&3) -> same-slot rows r,r+8 share banks (2-way
// aliasing = free, m136); staged by pre-permuting the GLOBAL chunk per lane
// (gload_lds dest must stay lane-linear, m104/m173).
// Schedule per K-tile t (buf c=t&1), staging tile t+1 into c^1:
//   P0: rd A-frags(qi0,ks0)+B(ks0) | stage A-kh0(t+1) | BAR lgkm0 prio1 16MFMA prio0 BAR
//   P1: rd A(qi1,ks0)              | stage B-kh0(t+1) | ... MFMA ... vmcnt(4) BAR
//   P2: rd A(qi0,ks1)+B(ks1)       | stage A-kh1(t+1) | ... MFMA ... BAR
//   P3: rd A(qi1,ks1)              | stage B-kh1(t+1) | ... MFMA ... vmcnt(4) BAR
// vmcnt(4) at P1 drains kh1(t) (oldest 4), at P3 drains kh0(t+1): counted, never 0
// in the main loop (T4). Last tile peeled (vmcnt(0) allowed in epilogue only).
template <int NT>
__device__ __forceinline__ void gemm_core256(unsigned short* __restrict__ Ls,
                                             const unsigned short* __restrict__ A,
                                             const unsigned short* __restrict__ B,
                                             unsigned short* __restrict__ C, int lda,
                                             int ldb, int ldc, long coff, int m0, int n0) {
  unsigned short* As = Ls;          // [4][256][32] ushort = 32768
  unsigned short* Bs = Ls + 32768;  // same
  const int tid = threadIdx.x;
  const int wid = tid >> 6, lane = tid & 63;
  const int wm = (wid >> 2) * 128, wn = (wid & 3) * 64;
  const int rq = lane >> 4, rl = lane & 15;
  const int phi = (rl >> 1) & 3;  // == (row>>1)&3 for rows = 16*const + rl

  f32x4 acc[8][4];
#pragma unroll
  for (int i = 0; i < 8; ++i)
#pragma unroll
    for (int j = 0; j < 4; ++j) acc[i][j] = (f32x4){0.f, 0.f, 0.f, 0.f};

  // --- staging lane constants: wave covers rows wid*32..+32 of each operand tile.
  // one gload = 16 rows x 32k; lane l -> row +(l>>2), slot l&3, global chunk
  // cg = (l&3)^((l>>3)&3)  (inverse-swizzled source, linear LDS dest).
  const int cg = (((lane & 3) ^ ((lane >> 3) & 3)) << 3);
  const int rr = lane >> 2;
  const unsigned short* Ag = &A[(long)(m0 + wid * 32 + rr) * lda + cg];
  const unsigned short* Bg = &B[(long)(n0 + wid * 32 + rr) * ldb + cg];
  unsigned short* AsW = As + wid * 1024;  // (wid*32 rows)*32
  unsigned short* BsW = Bs + wid * 1024;
  const long a16 = (long)16 * lda, b16 = (long)16 * ldb;

  auto stageA = [&](int buf, int kh, int kcol) {
    unsigned short* d = AsW + (buf * 2 + kh) * 8192;
    const unsigned short* g = Ag + kcol + (kh << 5);
#if HAVE_GLL
    gload_lds16(g, d);
    gload_lds16(g + a16, d + 512);
#else
    *reinterpret_cast<uint4*>(d + lane * 8) = *reinterpret_cast<const uint4*>(g);
    *reinterpret_cast<uint4*>(d + 512 + lane * 8) =
        *reinterpret_cast<const uint4*>(g + a16);
#endif
  };
  auto stageB = [&](int buf, int kh, int kcol) {
    unsigned short* d = BsW + (buf * 2 + kh) * 8192;
    const unsigned short* g = Bg + kcol + (kh << 5);
#if HAVE_GLL
    gload_lds16(g, d);
    gload_lds16(g + b16, d + 512);
#else
    *reinterpret_cast<uint4*>(d + lane * 8) = *reinterpret_cast<const uint4*>(g);
    *reinterpret_cast<uint4*>(d + 512 + lane * 8) =
        *reinterpret_cast<const uint4*>(g + b16);
#endif
  };
  auto rdA = [&](f16x8* af, int buf, int ks, int qi) {
    const unsigned short* p = As + (buf * 2 + ks) * 8192;
#pragma unroll
    for (int i = 0; i < 4; ++i) {
      int ra = wm + qi * 64 + i * 16 + rl;
      af[i] = *reinterpret_cast<const f16x8*>(&p[ra * 32 + ((rq ^ phi) << 3)]);
    }
  };
  auto rdB = [&](f16x8* bf, int buf, int ks) {
    const unsigned short* p = Bs + (buf * 2 + ks) * 8192;
#pragma unroll
    for (int j = 0; j < 4; ++j) {
      int rb = wn + j * 16 + rl;
      bf[j] = *reinterpret_cast<const f16x8*>(&p[rb * 32 + ((rq ^ phi) << 3)]);
    }
  };
  auto mm = [&](f16x8* af, f16x8* bf, int qi) {
    __builtin_amdgcn_s_setprio(1);
#pragma unroll
    for (int i = 0; i < 4; ++i)
#pragma unroll
      for (int j = 0; j < 4; ++j)
        acc[qi * 4 + i][j] = __builtin_amdgcn_mfma_f32_16x16x32_f16(
            af[i], bf[j], acc[qi * 4 + i][j], 0, 0, 0);
    __builtin_amdgcn_s_setprio(0);
  };

  // prologue: tile 0, issue order A-kh0, B-kh0, A-kh1, B-kh1 (vmcnt counts on this)
  stageA(0, 0, 0);
  stageB(0, 0, 0);
  stageA(0, 1, 0);
  stageB(0, 1, 0);
  WAITV(4);  // kh0 A+B landed; kh1 (4 loads) still in flight
  BAR;

  for (int t = 0; t < NT - 1; ++t) {
    const int cur = t & 1, nxt = cur ^ 1;
    const int kn = (t + 1) * 64;
    f16x8 a0[4], a1[4], b0[4], b1[4];
    // P0
    rdA(a0, cur, 0, 0);
    rdB(b0, cur, 0);
    stageA(nxt, 0, kn);
    BAR;
    WAITL0;
    mm(a0, b0, 0);
    BAR;
    // P1
    rdA(a1, cur, 0, 1);
    stageB(nxt, 0, kn);
    BAR;
    WAITL0;
    mm(a1, b0, 1);
    WAITV(4);  // drains kh1(t); leaves kh0(t+1)
    BAR;
    // P2
    rdA(a0, cur, 1, 0);
    rdB(b1, cur, 1);
    stageA(nxt, 1, kn);
    BAR;
    WAITL0;
    mm(a0, b1, 0);
    BAR;
    // P3
    rdA(a1, cur, 1, 1);
    stageB(nxt, 1, kn);
    BAR;
    WAITL0;
    mm(a1, b1, 1);
    WAITV(4);  // drains kh0(t+1); leaves kh1(t+1)
    BAR;
  }
  {  // peeled last tile: no staging; epilogue drain allowed
    const int cur = (NT - 1) & 1;
    f16x8 a0[4], a1[4], b0[4], b1[4];
    rdA(a0, cur, 0, 0);
    rdB(b0, cur, 0);
    BAR;
    WAITL0;
    mm(a0, b0, 0);
    BAR;
    rdA(a1, cur, 0, 1);
    BAR;
    WAITL0;
    mm(a1, b0, 1);
    WAITV(0);  // kh1(last) is all that's left
    BAR;
    rdA(a0, cur, 1, 0);
    rdB(b1, cur, 1);
    BAR;
    WAITL0;
    mm(a0, b1, 0);
    BAR;
    rdA(a1, cur, 1, 1);
    BAR;
    WAITL0;
    mm(a1, b1, 1);
  }

#pragma unroll
  for (int i = 0; i < 8; ++i)
#pragma unroll
    for (int j = 0; j < 4; ++j)
#pragma unroll
      for (int r = 0; r < 4; ++r) {
        int row = m0 + wm + i * 16 + rq * 4 + r;
        int col = n0 + wn + j * 16 + rl;
        C[coff + (long)row * ldc + col] = f2h(acc[i][j][r]);
      }
}

// ---------------- legacy 128x128 GEMM core (k_gemm_out only) ----------------
// OUT: 0 fp32 store, 1 fp16 store. BVU: B rows live in VUt[h*512+e][b*1024+j].
template <int OUT, int BVU>
__device__ __forceinline__ void gemm_core(unsigned short* __restrict__ As,
                                          unsigned short* __restrict__ Bs,
                                          const unsigned short* __restrict__ A,
                                          const unsigned short* __restrict__ B,
                                          void* __restrict__ Cv, int K, int lda, int ldb,
                                          int ldc, long coff, int m0, int n0, int kbase) {
  int tid = threadIdx.x;
  int wid = tid >> 6, lane = tid & 63;
  int wm = (wid >> 1) * 64, wn = (wid & 1) * 64;
  int rq = lane >> 4, rl = lane & 15;

  f32x4 acc[4][4];
#pragma unroll
  for (int i = 0; i < 4; ++i)
#pragma unroll
    for (int j = 0; j < 4; ++j) acc[i][j] = (f32x4){0.f, 0.f, 0.f, 0.f};

#if HAVE_GLL
  int cg = (lane & 7) ^ ((lane >> 3) & 7);
  int rl8 = lane >> 3;
#endif

  for (int k0 = 0; k0 < K; k0 += 64) {
    long bko;
    if (BVU) {
      int kk = kbase + k0;
      bko = (long)(kk >> 10) * 2097152 + (kk & 1023);
    } else {
      bko = k0;
    }
    __syncthreads();
#if HAVE_GLL
#pragma unroll
    for (int t = 0; t < 4; ++t) {
      int r = wid * 32 + t * 8;
      gload_lds16(&A[(long)(m0 + r + rl8) * lda + k0 + cg * 8], &As[r * 64]);
      gload_lds16(&B[(long)(n0 + r + rl8) * ldb + bko + cg * 8], &Bs[r * 64]);
    }
#else
#pragma unroll
    for (int it = 0; it < 4; ++it) {
      int idx = tid + it * 256;
      int r = idx >> 3, c = idx & 7;
      int cs = c ^ (r & 7);
      *reinterpret_cast<uint4*>(&As[r * 64 + cs * 8]) =
          *reinterpret_cast<const uint4*>(&A[(long)(m0 + r) * lda + k0 + c * 8]);
      *reinterpret_cast<uint4*>(&Bs[r * 64 + cs * 8]) =
          *reinterpret_cast<const uint4*>(&B[(long)(n0 + r) * ldb + bko + c * 8]);
    }
#endif
    __syncthreads();
#pragma unroll
    for (int ks = 0; ks < 2; ++ks) {
      f16x8 af[4], bfr[4];
      int kc = ks * 4 + rq;
#pragma unroll
      for (int i = 0; i < 4; ++i) {
        int ra = wm + i * 16 + rl;
        af[i] = *reinterpret_cast<const f16x8*>(&As[ra * 64 + ((kc ^ (ra & 7)) << 3)]);
        int rb = wn + i * 16 + rl;
        bfr[i] = *reinterpret_cast<const f16x8*>(&Bs[rb * 64 + ((kc ^ (rb & 7)) << 3)]);
      }
#pragma unroll
      for (int i = 0; i < 4; ++i)
#pragma unroll
        for (int j = 0; j < 4; ++j)
          acc[i][j] = __builtin_amdgcn_mfma_f32_16x16x32_f16(af[i], bfr[j], acc[i][j], 0, 0, 0);
    }
  }

#pragma unroll
  for (int i = 0; i < 4; ++i)
#pragma unroll
    for (int j = 0; j < 4; ++j)
#pragma unroll
      for (int r = 0; r < 4; ++r) {
        int row = m0 + wm + i * 16 + rq * 4 + r;
        int col = n0 + wn + j * 16 + rl;
        float v = acc[i][j][r];
        if (OUT == 1)
          reinterpret_cast<unsigned short*>(Cv)[coff + (long)row * ldc + col] = f2h(v);
        else
          reinterpret_cast<float*>(Cv)[coff + (long)row * ldc + col] = v;
      }
}

// ---------------- w_core: 128x128xBK64 gemm staging from RAW fp32 ----------------
__device__ __forceinline__ void w_core(unsigned short* __restrict__ As,
                                       unsigned short* __restrict__ Bs,
                                       const float* __restrict__ A32,
                                       const float* __restrict__ B32,
                                       unsigned short* __restrict__ C,
                                       int lda, int ldb, bool atrans, int m0, int n0) {
  int tid = threadIdx.x;
  int wid = tid >> 6, lane = tid & 63;
  int wm = (wid >> 1) * 64, wn = (wid & 1) * 64;
  int rq = lane >> 4, rl = lane & 15;

  f32x4 acc[4][4];
#pragma unroll
  for (int i = 0; i < 4; ++i)
#pragma unroll
    for (int j = 0; j < 4; ++j) acc[i][j] = (f32x4){0.f, 0.f, 0.f, 0.f};

  for (int k0 = 0; k0 < 512; k0 += 64) {
    __syncthreads();
    if (!atrans) {
#pragma unroll
      for (int it = 0; it < 8; ++it) {
        int idx = it * 256 + tid;
        int r = idx >> 4, kq = idx & 15;
        float4 v = *reinterpret_cast<const float4*>(&A32[(long)(m0 + r) * lda + k0 + kq * 4]);
        ushort4 u;
        u.x = f2h(v.x); u.y = f2h(v.y); u.z = f2h(v.z); u.w = f2h(v.w);
        int cs = (kq >> 1) ^ (r & 7);
        *reinterpret_cast<ushort4*>(&As[r * 64 + cs * 8 + (kq & 1) * 4]) = u;
      }
    } else {
#pragma unroll
      for (int it = 0; it < 32; ++it) {
        int idx = it * 256 + tid;
        int m = idx & 127, d = idx >> 7;
        float v = A32[(long)(k0 + d) * 512 + m0 + m];
        int cs = (d >> 3) ^ (m & 7);
        As[m * 64 + cs * 8 + (d & 7)] = f2h(v);
      }
    }
#pragma unroll
    for (int it = 0; it < 8; ++it) {
      int idx = it * 256 + tid;
      int r = idx >> 4, kq = idx & 15;
      float4 v = *reinterpret_cast<const float4*>(&B32[(long)(n0 + r) * ldb + k0 + kq * 4]);
      ushort4 u;
      u.x = f2h(v.x); u.y = f2h(v.y); u.z = f2h(v.z); u.w = f2h(v.w);
      int cs = (kq >> 1) ^ (r & 7);
      *reinterpret_cast<ushort4*>(&Bs[r * 64 + cs * 8 + (kq & 1) * 4]) = u;
    }
    __syncthreads();
#pragma unroll
    for (int ks = 0; ks < 2; ++ks) {
      f16x8 af[4], bfr[4];
      int kc = ks * 4 + rq;
#pragma unroll
      for (int i = 0; i < 4; ++i) {
        int ra = wm + i * 16 + rl;
        af[i] = *reinterpret_cast<const f16x8*>(&As[ra * 64 + ((kc ^ (ra & 7)) << 3)]);
        int rb = wn + i * 16 + rl;
        bfr[i] = *reinterpret_cast<const f16x8*>(&Bs[rb * 64 + ((kc ^ (rb & 7)) << 3)]);
      }
#pragma unroll
      for (int i = 0; i < 4; ++i)
#pragma unroll
        for (int j = 0; j < 4; ++j)
          acc[i][j] = __builtin_amdgcn_mfma_f32_16x16x32_f16(af[i], bfr[j], acc[i][j], 0, 0, 0);
    }
  }

#pragma unroll
  for (int i = 0; i < 4; ++i)
#pragma unroll
    for (int j = 0; j < 4; ++j)
#pragma unroll
      for (int r = 0; r < 4; ++r) {
        int row = m0 + wm + i * 16 + rq * 4 + r;
        int col = n0 + wn + j * 16 + rl;
        C[(long)row * 512 + col] = f2h(acc[i][j][r]);
      }
}

#define DECL_LDS \
  __shared__ unsigned short As[128 * 64]; \
  __shared__ unsigned short Bs[128 * 64];

// L1 (setup+folds merged): grid (8, 288). Unchanged.
__global__ __launch_bounds__(256, 2) void k_wsetup(
    const float* __restrict__ x, const float* __restrict__ Wq, const float* __restrict__ Wk,
    const float* __restrict__ Wv, const float* __restrict__ Wu,
    unsigned short* __restrict__ Xh, unsigned short* __restrict__ Gt,
    unsigned short* __restrict__ Wvut) {
  DECL_LDS
  int c = blockIdx.x, w = blockIdx.y;
  if (w >= 32) {
    int i = ((w - 32) * 8 + c) * 256 + threadIdx.x;
    float4 v = reinterpret_cast<const float4*>(x)[i];
    ushort4 u;
    u.x = f2h(v.x); u.y = f2h(v.y); u.z = f2h(v.z); u.w = f2h(v.w);
    reinterpret_cast<ushort4*>(Xh)[i] = u;
    return;
  }
  const float *A32, *B32;
  unsigned short* C;
  int lda;
  bool atrans;
  int t;
  if (w < 16) {
    A32 = Wq + c * 512; B32 = Wk + c * 512; C = Gt + (long)c * 262144;
    lda = 4096; atrans = false; t = w;
  } else {
    A32 = Wu + (long)c * 262144; B32 = Wv + c * 512; C = Wvut + (long)c * 262144;
    lda = 512; atrans = true; t = w - 16;
  }
  w_core(As, Bs, A32, B32, C, lda, 4096, atrans, (t >> 2) * 128, (t & 3) * 128);
}

// L2: T + VU projections fused, NOW 256x256 8-phase. grid (8,64) x 512 thr.
// w<32 : T[bt][c*512+n] = sum_a X[bt,a] * Gt_c[n,a]         (M=4096, N=512/head)
// w>=32: VUt[c*512+e][bt] = sum_k Wvut_c[e,k] * X[bt,k]      (M=512/head, N=4096)
// Both legs share lda=ldb=512, ldc=4096 -> single core call (one instantiation).
__global__ __launch_bounds__(512, 2) void k_gemm_tv(
    const unsigned short* __restrict__ X, const unsigned short* __restrict__ Gt,
    const unsigned short* __restrict__ Wvut, unsigned short* __restrict__ T,
    unsigned short* __restrict__ VUt) {
  __shared__ unsigned short Ls[65536];  // 128 KiB
  int c = blockIdx.x, w = blockIdx.y;
  const unsigned short *A, *B;
  unsigned short* C;
  long coff;
  int m0, n0;
  if (w < 32) {
    A = X; B = Gt + (long)c * 262144; C = T;
    coff = (long)c * 512; m0 = (w >> 1) * 256; n0 = (w & 1) * 256;
  } else {
    int wp = w - 32;
    A = Wvut; B = X; C = VUt;
    coff = 0; m0 = c * 512 + (wp & 1) * 256; n0 = (wp >> 1) * 256;
  }
  gemm_core256<8>(Ls, A, B, C, 512, 512, 4096, coff, m0, n0);
}

// L3: S-gemm, NOW 256x256 8-phase. grid (8,64) x 512 thr. h = c (XCD-pinned),
// b = w>>4, 16 tiles of 256^2 over the 1024x1024 per-(b,h) score block.
__global__ __launch_bounds__(512, 2) void k_gemm_s(
    const unsigned short* __restrict__ X, const unsigned short* __restrict__ T,
    unsigned short* __restrict__ Pb) {
  __shared__ unsigned short Ls[65536];
  int c = blockIdx.x, w = blockIdx.y;
  int b = w >> 4, t = w & 15;
  gemm_core256<8>(Ls, T + (long)b * 4194304 + c * 512, X + (long)b * 524288, Pb,
                  4096, 512, 8192, (long)b * 8388608 + c * 1024,
                  ((t >> 2) & 3) * 256, (t & 3) * 256);
}

// L5: O-partials (legacy 128^2 core, unchanged): grid (8,64) x 256.
__global__ __launch_bounds__(256, 2) void k_gemm_out(
    const unsigned short* __restrict__ Pb, const unsigned short* __restrict__ VUt,
    float* __restrict__ Opart) {
  DECL_LDS
  int c = blockIdx.x, w = blockIdx.y;
  int g = c + 8 * (w >> 4);
  int r = w & 15;
  int b = g >> 3, kc = (g >> 1) & 3, ih = g & 1;
  int y = ih * 4 + (r >> 2);
  int x = r & 3;
  gemm_core<0, 1>(As, Bs, Pb + (long)b * 8388608 + kc * 2048, VUt + (long)b * 1024,
                  Opart, 2048, 8192, 4096, 512,
                  (long)kc * 2097152 + (long)b * 524288, y * 128, x * 128, kc * 2048);
}

// L6: out[i] = sum_kc Opart[kc][i].
__global__ __launch_bounds__(256) void k_reduce(const float* __restrict__ Opart,
                                                float* __restrict__ out) {
  int i = blockIdx.x * 256 + threadIdx.x;
  float4 a = reinterpret_cast<const float4*>(Opart)[i];
  float4 b = reinterpret_cast<const float4*>(Opart + 2097152)[i];
  float4 c = reinterpret_cast<const float4*>(Opart + 4194304)[i];
  float4 d = reinterpret_cast<const float4*>(Opart + 6291456)[i];
  float4 o;
  o.x = (a.x + b.x) + (c.x + d.x);
  o.y = (a.y + b.y) + (c.y + d.y);
  o.z = (a.z + b.z) + (c.z + d.z);
  o.w = (a.w + b.w) + (c.w + d.w);
  reinterpret_cast<float4*>(out)[i] = o;
}

// L4: softmax, one wave per 1024-chunk of P[b][i][h*1024+j], in place. Unchanged.
__global__ __launch_bounds__(256) void k_softmax_x(unsigned short* __restrict__ S) {
  int g = blockIdx.y * 4 + (threadIdx.x >> 6);
  int b = g >> 10, i = g & 1023;
  long base = (long)b * 8388608 + (long)i * 8192 + (long)blockIdx.x * 1024;
  int lane = threadIdx.x & 63;
  f16x8* p = reinterpret_cast<f16x8*>(S + base);
  f16x8 a = p[lane * 2], bb = p[lane * 2 + 1];
  float v[16];
#pragma unroll
  for (int q = 0; q < 8; ++q) { v[q] = (float)a[q]; v[8 + q] = (float)bb[q]; }
  float m = v[0];
#pragma unroll
  for (int q = 1; q < 16; ++q) m = fmaxf(m, v[q]);
#pragma unroll
  for (int o = 32; o; o >>= 1) m = fmaxf(m, __shfl_xor(m, o));
  float s = 0.f;
#pragma unroll
  for (int q = 0; q < 16; ++q) { v[q] = __expf(v[q] - m); s += v[q]; }
#pragma unroll
  for (int o = 32; o; o >>= 1) s += __shfl_xor(s, o);
  float inv = 1.0f / s;
  f16x8 oa, ob;
#pragma unroll
  for (int q = 0; q < 8; ++q) {
    oa[q] = (_Float16)(v[q] * inv);
    ob[q] = (_Float16)(v[8 + q] * inv);
  }
  p[lane * 2] = oa;
  p[lane * 2 + 1] = ob;
}

__global__ void k_sentinel(float* out, float v) { out[0] = v; }

extern "C" void kernel_launch(void* const* d_in, const int* in_sizes, int n_in,
                              void* d_out, int out_size, void* d_ws, size_t ws_size,
                              hipStream_t stream) {
  // setup_inputs dict order: x, Wk, Wq, Wv, Wu
  const float* x  = (const float*)d_in[0];
  const float* Wk = (const float*)d_in[1];
  const float* Wq = (const float*)d_in[2];
  const float* Wv = (const float*)d_in[3];
  const float* Wu = (const float*)d_in[4];
  float* out = (float*)d_out;

  const long SZ_X = 4096L * 512;
  const size_t NEED = 150994944;  // 144 MiB

  if (ws_size < NEED) {
    hipMemsetAsync(d_out, 0, (size_t)out_size * 4, stream);
    k_sentinel<<<1, 1, 0, stream>>>(out, (float)ws_size);
    return;
  }

  char* p = (char*)d_ws;
  unsigned short* Xbf  = (unsigned short*)p; p += SZ_X * 2;           //  4 MiB
  unsigned short* Wvut = (unsigned short*)p; p += 8L * 512 * 512 * 2; //  4 MiB [h][e][k]
  unsigned short* Gt   = (unsigned short*)p; p += 8L * 512 * 512 * 2; //  4 MiB [h][b'][a]
  unsigned short* T    = (unsigned short*)p; p += 4096L * 4096 * 2;   // 32 MiB [bt][h*512+b']
  unsigned short* Pb   = (unsigned short*)p; p += 4096L * 8192 * 2;   // 64 MiB [b][i][h*1024+j]
  unsigned short* VUt  = (unsigned short*)p;                          // 32 MiB [h*512+e][b*1024+j]
  float* Opart = (float*)T;  // 32 MiB alias: T dead after S-gemm

  // L1: x convert + weight folds
  k_wsetup<<<dim3(8, 288), 256, 0, stream>>>(x, Wq, Wk, Wv, Wu, Xbf, Gt, Wvut);

  // L2: T = X.Gt^T + VU^T = Wvut.X^T, 256^2 8-phase
  k_gemm_tv<<<dim3(8, 64), 512, 0, stream>>>(Xbf, Gt, Wvut, T, VUt);

  // L3: P = T.X^T, 256^2 8-phase
  k_gemm_s<<<dim3(8, 64), 512, 0, stream>>>(Xbf, T, Pb);

  // L4: softmax over each 1024-chunk of P, in place
  k_softmax_x<<<dim3(8, 1024), 256, 0, stream>>>(Pb);

  // L5: out partials = P . VU^T
  k_gemm_out<<<dim3(8, 64), 256, 0, stream>>>(Pb, VUt, Opart);

  // L6: out = sum of 4 partials
  k_reduce<<<2048, 256, 0, stream>>>(Opart, out);
}

// Round 2
// 251.894 us; speedup vs baseline: 1.0407x; 1.0407x over previous
//
#include <hip/hip_runtime.h>
#include <stdint.h>

typedef _Float16 f16x8 __attribute__((ext_vector_type(8)));
typedef float f32x4 __attribute__((ext_vector_type(4)));

__device__ __forceinline__ unsigned short f2h(float f) {
  _Float16 h = (_Float16)f;
  return __builtin_bit_cast(unsigned short, h);
}

#if __has_builtin(__builtin_amdgcn_global_load_lds)
#define HAVE_GLL 1
__device__ __forceinline__ void gload_lds16(const void* g, void* l) {
  auto gp = reinterpret_cast<const __attribute__((address_space(1))) void*>(
      reinterpret_cast<uintptr_t>(g));
  auto lp = reinterpret_cast<__attribute__((address_space(3))) void*>(
      reinterpret_cast<uintptr_t>(l));
  __builtin_amdgcn_global_load_lds(gp, lp, 16, 0, 0);
}
#else
#define HAVE_GLL 0
#endif

// ---------------- GEMM core: C[M,N] = A[M,K] * B[N,K]^T (fp16 inputs) ----------------
// 128x128 tile, BK=64, 256 threads (4 waves, 2x2 of 64x64), mfma 16x16x32 f16.
// LDS XOR-swizzled at 16B granularity; staging via global_load_lds(16B).
// PROVEN structure (R0 baseline, 765 TF on these shapes). R12's 8-phase 256^2 port
// REGRESSED (MfmaUtil 30->23, -20%): custom derived-waits != m201 template (m232
// lesson). Reverted; do not re-derive sync structures blindly.
// OUT: 0 fp32 store, 1 fp16 store. BVU: B rows live in VUt[h*512+e][b*1024+j].
// SMAX: epilogue computes per-row (max, sum-exp) over this block's 128 cols,
// writes P~ = exp(v - m_local) fp16 + (m,s) stats; consumer rescales (online
// softmax two-level combine). One template instantiation per kernel (R8/R9).
template <int OUT, int BVU, int SMAX>
__device__ __forceinline__ void gemm_core(unsigned short* __restrict__ As,
                                          unsigned short* __restrict__ Bs,
                                          const unsigned short* __restrict__ A,
                                          const unsigned short* __restrict__ B,
                                          void* __restrict__ Cv, int K, int lda, int ldb,
                                          int ldc, long coff, int m0, int n0, int kbase,
                                          float2* __restrict__ stats, long sbase) {
  int tid = threadIdx.x;
  int wid = tid >> 6, lane = tid & 63;
  int wm = (wid >> 1) * 64, wn = (wid & 1) * 64;
  int rq = lane >> 4, rl = lane & 15;

  f32x4 acc[4][4];
#pragma unroll
  for (int i = 0; i < 4; ++i)
#pragma unroll
    for (int j = 0; j < 4; ++j) acc[i][j] = (f32x4){0.f, 0.f, 0.f, 0.f};

#if HAVE_GLL
  int cg = (lane & 7) ^ ((lane >> 3) & 7);  // permuted global chunk -> swizzled LDS
  int rl8 = lane >> 3;                      // row within 8-row group
#endif

  for (int k0 = 0; k0 < K; k0 += 64) {
    long bko;
    if (BVU) {
      int kk = kbase + k0;
      bko = (long)(kk >> 10) * 2097152 + (kk & 1023);
    } else {
      bko = k0;
    }
    __syncthreads();
#if HAVE_GLL
#pragma unroll
    for (int t = 0; t < 4; ++t) {
      int r = wid * 32 + t * 8;  // uniform slab base row
      gload_lds16(&A[(long)(m0 + r + rl8) * lda + k0 + cg * 8], &As[r * 64]);
      gload_lds16(&B[(long)(n0 + r + rl8) * ldb + bko + cg * 8], &Bs[r * 64]);
    }
#else
#pragma unroll
    for (int it = 0; it < 4; ++it) {
      int idx = tid + it * 256;
      int r = idx >> 3, c = idx & 7;
      int cs = c ^ (r & 7);
      *reinterpret_cast<uint4*>(&As[r * 64 + cs * 8]) =
          *reinterpret_cast<const uint4*>(&A[(long)(m0 + r) * lda + k0 + c * 8]);
      *reinterpret_cast<uint4*>(&Bs[r * 64 + cs * 8]) =
          *reinterpret_cast<const uint4*>(&B[(long)(n0 + r) * ldb + bko + c * 8]);
    }
#endif
    __syncthreads();
#pragma unroll
    for (int ks = 0; ks < 2; ++ks) {
      f16x8 af[4], bfr[4];
      int kc = ks * 4 + rq;
#pragma unroll
      for (int i = 0; i < 4; ++i) {
        int ra = wm + i * 16 + rl;
        af[i] = *reinterpret_cast<const f16x8*>(&As[ra * 64 + ((kc ^ (ra & 7)) << 3)]);
        int rb = wn + i * 16 + rl;
        bfr[i] = *reinterpret_cast<const f16x8*>(&Bs[rb * 64 + ((kc ^ (rb & 7)) << 3)]);
      }
#pragma unroll
      for (int i = 0; i < 4; ++i)
#pragma unroll
        for (int j = 0; j < 4; ++j)
          acc[i][j] = __builtin_amdgcn_mfma_f32_16x16x32_f16(af[i], bfr[j], acc[i][j], 0, 0, 0);
    }
  }

  if constexpr (SMAX) {
    // ---- per-row local softmax stats over this block's 128 cols ----
    // Row of acc elem (i,_,r): wm + i*16 + rq*4 + r; cols: wn + j*16 + rl.
    // Lanes sharing a row differ only in rl (bits 0..3) -> shfl_xor 1/2/4/8.
    __syncthreads();  // all waves done reading As/Bs; reuse As as f32 scratch
    float* tmx = reinterpret_cast<float*>(As);  // [2][128] per-column-wave max
    float* tsm = tmx + 256;                     // [2][128] per-column-wave sum
    int wp = wid & 1;
#pragma unroll
    for (int i = 0; i < 4; ++i)
#pragma unroll
      for (int r = 0; r < 4; ++r) {
        float mx = fmaxf(fmaxf(acc[i][0][r], acc[i][1][r]),
                         fmaxf(acc[i][2][r], acc[i][3][r]));
#pragma unroll
        for (int o = 1; o < 16; o <<= 1) mx = fmaxf(mx, __shfl_xor(mx, o));
        if (rl == 0) tmx[wp * 128 + wm + i * 16 + rq * 4 + r] = mx;
      }
    __syncthreads();
#pragma unroll
    for (int i = 0; i < 4; ++i)
#pragma unroll
      for (int r = 0; r < 4; ++r) {
        int row = wm + i * 16 + rq * 4 + r;
        float m = fmaxf(tmx[row], tmx[128 + row]);
        float s = 0.f;
#pragma unroll
        for (int j = 0; j < 4; ++j) {
          float e = __expf(acc[i][j][r] - m);
          acc[i][j][r] = e;  // store exp'd value; C-write emits P~
          s += e;
        }
#pragma unroll
        for (int o = 1; o < 16; o <<= 1) s += __shfl_xor(s, o);
        if (rl == 0) tsm[wp * 128 + row] = s;
      }
    __syncthreads();
    if (tid < 128) {
      int row = tid;
      float m = fmaxf(tmx[row], tmx[128 + row]);
      float s = tsm[row] + tsm[128 + row];
      stats[sbase + (long)row * 8] = make_float2(m, s);
    }
  }

#pragma unroll
  for (int i = 0; i < 4; ++i)
#pragma unroll
    for (int j = 0; j < 4; ++j)
#pragma unroll
      for (int r = 0; r < 4; ++r) {
        int row = m0 + wm + i * 16 + rq * 4 + r;
        int col = n0 + wn + j * 16 + rl;
        float v = acc[i][j][r];
        if (OUT == 1)
          reinterpret_cast<unsigned short*>(Cv)[coff + (long)row * ldc + col] = f2h(v);
        else
          reinterpret_cast<float*>(Cv)[coff + (long)row * ldc + col] = v;
      }
}

// ---------------- w_core: same 128x128xBK64 gemm but staging from RAW fp32 ----------------
__device__ __forceinline__ void w_core(unsigned short* __restrict__ As,
                                       unsigned short* __restrict__ Bs,
                                       const float* __restrict__ A32,
                                       const float* __restrict__ B32,
                                       unsigned short* __restrict__ C,
                                       int lda, int ldb, bool atrans, int m0, int n0) {
  int tid = threadIdx.x;
  int wid = tid >> 6, lane = tid & 63;
  int wm = (wid >> 1) * 64, wn = (wid & 1) * 64;
  int rq = lane >> 4, rl = lane & 15;

  f32x4 acc[4][4];
#pragma unroll
  for (int i = 0; i < 4; ++i)
#pragma unroll
    for (int j = 0; j < 4; ++j) acc[i][j] = (f32x4){0.f, 0.f, 0.f, 0.f};

  for (int k0 = 0; k0 < 512; k0 += 64) {
    __syncthreads();
    if (!atrans) {
#pragma unroll
      for (int it = 0; it < 8; ++it) {
        int idx = it * 256 + tid;
        int r = idx >> 4, kq = idx & 15;
        float4 v = *reinterpret_cast<const float4*>(&A32[(long)(m0 + r) * lda + k0 + kq * 4]);
        ushort4 u;
        u.x = f2h(v.x); u.y = f2h(v.y); u.z = f2h(v.z); u.w = f2h(v.w);
        int cs = (kq >> 1) ^ (r & 7);
        *reinterpret_cast<ushort4*>(&As[r * 64 + cs * 8 + (kq & 1) * 4]) = u;
      }
    } else {
#pragma unroll
      for (int it = 0; it < 32; ++it) {
        int idx = it * 256 + tid;
        int m = idx & 127, d = idx >> 7;  // coalesced over m (128x4B runs)
        float v = A32[(long)(k0 + d) * 512 + m0 + m];
        int cs = (d >> 3) ^ (m & 7);
        As[m * 64 + cs * 8 + (d & 7)] = f2h(v);
      }
    }
#pragma unroll
    for (int it = 0; it < 8; ++it) {
      int idx = it * 256 + tid;
      int r = idx >> 4, kq = idx & 15;
      float4 v = *reinterpret_cast<const float4*>(&B32[(long)(n0 + r) * ldb + k0 + kq * 4]);
      ushort4 u;
      u.x = f2h(v.x); u.y = f2h(v.y); u.z = f2h(v.z); u.w = f2h(v.w);
      int cs = (kq >> 1) ^ (r & 7);
      *reinterpret_cast<ushort4*>(&Bs[r * 64 + cs * 8 + (kq & 1) * 4]) = u;
    }
    __syncthreads();
#pragma unroll
    for (int ks = 0; ks < 2; ++ks) {
      f16x8 af[4], bfr[4];
      int kc = ks * 4 + rq;
#pragma unroll
      for (int i = 0; i < 4; ++i) {
        int ra = wm + i * 16 + rl;
        af[i] = *reinterpret_cast<const f16x8*>(&As[ra * 64 + ((kc ^ (ra & 7)) << 3)]);
        int rb = wn + i * 16 + rl;
        bfr[i] = *reinterpret_cast<const f16x8*>(&Bs[rb * 64 + ((kc ^ (rb & 7)) << 3)]);
      }
#pragma unroll
      for (int i = 0; i < 4; ++i)
#pragma unroll
        for (int j = 0; j < 4; ++j)
          acc[i][j] = __builtin_amdgcn_mfma_f32_16x16x32_f16(af[i], bfr[j], acc[i][j], 0, 0, 0);
    }
  }

#pragma unroll
  for (int i = 0; i < 4; ++i)
#pragma unroll
    for (int j = 0; j < 4; ++j)
#pragma unroll
      for (int r = 0; r < 4; ++r) {
        int row = m0 + wm + i * 16 + rq * 4 + r;
        int col = n0 + wn + j * 16 + rl;
        C[(long)row * 512 + col] = f2h(acc[i][j][r]);
      }
}

#define DECL_LDS \
  __shared__ unsigned short As[128 * 64]; \
  __shared__ unsigned short Bs[128 * 64];

// L1 (setup+folds merged): grid (8, 288). Unchanged.
__global__ __launch_bounds__(256, 2) void k_wsetup(
    const float* __restrict__ x, const float* __restrict__ Wq, const float* __restrict__ Wk,
    const float* __restrict__ Wv, const float* __restrict__ Wu,
    unsigned short* __restrict__ Xh, unsigned short* __restrict__ Gt,
    unsigned short* __restrict__ Wvut) {
  DECL_LDS
  int c = blockIdx.x, w = blockIdx.y;
  if (w >= 32) {
    int i = ((w - 32) * 8 + c) * 256 + threadIdx.x;
    float4 v = reinterpret_cast<const float4*>(x)[i];
    ushort4 u;
    u.x = f2h(v.x); u.y = f2h(v.y); u.z = f2h(v.z); u.w = f2h(v.w);
    reinterpret_cast<ushort4*>(Xh)[i] = u;
    return;
  }
  const float *A32, *B32;
  unsigned short* C;
  int lda;
  bool atrans;
  int t;
  if (w < 16) {
    A32 = Wq + c * 512; B32 = Wk + c * 512; C = Gt + (long)c * 262144;
    lda = 4096; atrans = false; t = w;
  } else {
    A32 = Wu + (long)c * 262144; B32 = Wv + c * 512; C = Wvut + (long)c * 262144;
    lda = 512; atrans = true; t = w - 16;
  }
  w_core(As, Bs, A32, B32, C, lda, 4096, atrans, (t >> 2) * 128, (t & 3) * 128);
}

// L2: T + VU projections fused, grid (8,256), legacy core (reverted from 8-phase).
__global__ __launch_bounds__(256, 2) void k_gemm_tv(
    const unsigned short* __restrict__ X, const unsigned short* __restrict__ Gt,
    const unsigned short* __restrict__ Wvut, unsigned short* __restrict__ T,
    unsigned short* __restrict__ VUt) {
  DECL_LDS
  int c = blockIdx.x, w = blockIdx.y;
  const unsigned short *A, *B;
  unsigned short* C;
  long coff;
  int m0, n0;
  if (w < 128) {
    A = X; B = Gt + (long)c * 262144; C = T;
    coff = (long)c * 512; m0 = (w >> 2) * 128; n0 = (w & 3) * 128;
  } else {
    int wp = w - 128;
    A = Wvut; B = X; C = VUt;
    coff = 0; m0 = (4 * c + (wp & 3)) * 128; n0 = (wp >> 2) * 128;
  }
  gemm_core<1, 0, 0>(As, Bs, A, B, C, 512, 512, 512, 4096, coff, m0, n0, 0, nullptr, 0);
}

// L3: S-gemm + local-softmax epilogue, grid (8,256), legacy core + SMAX.
// Writes P~[b][i][h*1024+j] = exp(S - m_local(128-col tile)) fp16, and
// stats[b][h][i][seg] = (m_local, sum_exp_local), seg = n-tile (8 per head).
__global__ __launch_bounds__(256, 2) void k_gemm_s(
    const unsigned short* __restrict__ X, const unsigned short* __restrict__ T,
    unsigned short* __restrict__ Pb, float2* __restrict__ stats) {
  DECL_LDS
  int c = blockIdx.x, w = blockIdx.y;
  int z = c + 8 * (w >> 6), t = w & 63;
  int b = z >> 3, h = z & 7;
  long sbase = (((long)b * 8 + h) * 1024 + (t >> 3) * 128) * 8 + (t & 7);
  gemm_core<1, 0, 1>(As, Bs, T + (long)b * 4194304 + h * 512, X + (long)b * 524288, Pb,
                     512, 4096, 512, 8192, (long)b * 8388608 + h * 1024,
                     (t >> 3) * 128, (t & 7) * 128, 0, stats, sbase);
}

// L5: O-partials with fused softmax rescale. grid (8,64), fp32 stores.
// K-chunk kc covers heads {2kc, 2kc+1} COMPLETELY (2048 = 2 x 1024 cols), so this
// block can finish softmax: prologue combines the 8 per-seg stats per (row,head)
// into (M, 1/S), builds factor f[row][seg16] = exp(m_seg - M)/S; A-staging is
// reg-staged (P~ fp16 -> f32 * f -> fp16) into the same swizzled LDS layout.
__global__ __launch_bounds__(256, 2) void k_gemm_out(
    const unsigned short* __restrict__ Pb, const unsigned short* __restrict__ VUt,
    const float2* __restrict__ stats, float* __restrict__ Opart) {
  __shared__ unsigned short As[128 * 64];
  __shared__ unsigned short Bs[128 * 64];
  __shared__ float fct[128 * 16];  // 8 KiB: per (row, seg16) rescale factor
  __shared__ float MH[256];        // [row][hh] global max
  __shared__ float IH[256];        // [row][hh] 1/S
  int c = blockIdx.x, w = blockIdx.y;
  int g = c + 8 * (w >> 4);  // 0..31
  int r = w & 15;
  int b = g >> 3, kc = (g >> 1) & 3, ih = g & 1;
  int y = ih * 4 + (r >> 2);  // i-tile 0..7
  int x = r & 3;              // e-tile 0..3
  int m0 = y * 128, n0 = x * 128;
  const unsigned short* A = Pb + (long)b * 8388608 + kc * 2048;
  const unsigned short* Bp = VUt + (long)b * 1024;

  {  // step 1: (M, 1/S) per (row, head-half). 256 threads = 128 rows x 2 heads.
    int t = threadIdx.x, row = t >> 1, hh = t & 1;
    long sb = (((long)b * 8 + kc * 2 + hh) * 1024 + m0 + row) * 8;
    float2 st[8];
    float m = -3.4e38f;
#pragma unroll
    for (int k = 0; k < 8; ++k) { st[k] = stats[sb + k]; m = fmaxf(m, st[k].x); }
    float s = 0.f;
#pragma unroll
    for (int k = 0; k < 8; ++k) s += st[k].y * __expf(st[k].x - m);
    MH[t] = m;
    IH[t] = 1.0f / s;
  }
  __syncthreads();
#pragma unroll
  for (int it = 0; it < 8; ++it) {  // step 2: factors, 2048 = 128 rows x 16 segs
    int idx = threadIdx.x + it * 256;
    int row = idx >> 4, sg = idx & 15;
    int hh = sg >> 3, seg = sg & 7;
    float mseg = stats[(((long)b * 8 + kc * 2 + hh) * 1024 + m0 + row) * 8 + seg].x;
    fct[row * 16 + sg] = __expf(mseg - MH[row * 2 + hh]) * IH[row * 2 + hh];
  }

  int tid = threadIdx.x;
  int wid = tid >> 6, lane = tid & 63;
  int wm = (wid >> 1) * 64, wn = (wid & 1) * 64;
  int rq = lane >> 4, rl = lane & 15;
  f32x4 acc[4][4];
#pragma unroll
  for (int i = 0; i < 4; ++i)
#pragma unroll
    for (int j = 0; j < 4; ++j) acc[i][j] = (f32x4){0.f, 0.f, 0.f, 0.f};
#if HAVE_GLL
  int cg = (lane & 7) ^ ((lane >> 3) & 7);
  int rl8 = lane >> 3;
#endif

  for (int k0 = 0; k0 < 2048; k0 += 64) {
    int kk = kc * 2048 + k0;
    long bko = (long)(kk >> 10) * 2097152 + (kk & 1023);
    __syncthreads();  // (iter 0: also fences the fct prologue)
    // A: reg-staged with softmax rescale, swizzled ds_write (fallback layout).
    // k-tile lies within one 128-wide seg (k0 % 128 in {0,64}, +c*8 < 64).
#pragma unroll
    for (int it = 0; it < 4; ++it) {
      int idx = tid + it * 256;
      int rr = idx >> 3, cc = idx & 7;
      uint4 raw = *reinterpret_cast<const uint4*>(&A[(long)(m0 + rr) * 8192 + k0 + cc * 8]);
      float f = fct[rr * 16 + (k0 >> 7)];
      uint vv[4] = {raw.x, raw.y, raw.z, raw.w};
#pragma unroll
      for (int q = 0; q < 4; ++q) {
        _Float16 lo = __builtin_bit_cast(_Float16, (unsigned short)(vv[q] & 0xffffu));
        _Float16 hi = __builtin_bit_cast(_Float16, (unsigned short)(vv[q] >> 16));
        unsigned short slo = f2h((float)lo * f);
        unsigned short shi = f2h((float)hi * f);
        vv[q] = (uint)slo | ((uint)shi << 16);
      }
      uint4 outv = {vv[0], vv[1], vv[2], vv[3]};
      *reinterpret_cast<uint4*>(&As[rr * 64 + ((cc ^ (rr & 7)) << 3)]) = outv;
    }
    // B: direct-to-LDS as before
#if HAVE_GLL
#pragma unroll
    for (int t2 = 0; t2 < 4; ++t2) {
      int rr2 = wid * 32 + t2 * 8;
      gload_lds16(&Bp[(long)(n0 + rr2 + rl8) * 4096 + bko + cg * 8], &Bs[rr2 * 64]);
    }
#else
#pragma unroll
    for (int it = 0; it < 4; ++it) {
      int idx = tid + it * 256;
      int rr2 = idx >> 3, cc = idx & 7;
      int cs = cc ^ (rr2 & 7);
      *reinterpret_cast<uint4*>(&Bs[rr2 * 64 + cs * 8]) =
          *reinterpret_cast<const uint4*>(&Bp[(long)(n0 + rr2) * 4096 + bko + cc * 8]);
    }
#endif
    __syncthreads();
#pragma unroll
    for (int ks = 0; ks < 2; ++ks) {
      f16x8 af[4], bfr[4];
      int kcx = ks * 4 + rq;
#pragma unroll
      for (int i = 0; i < 4; ++i) {
        int ra = wm + i * 16 + rl;
        af[i] = *reinterpret_cast<const f16x8*>(&As[ra * 64 + ((kcx ^ (ra & 7)) << 3)]);
        int rb = wn + i * 16 + rl;
        bfr[i] = *reinterpret_cast<const f16x8*>(&Bs[rb * 64 + ((kcx ^ (rb & 7)) << 3)]);
      }
#pragma unroll
      for (int i = 0; i < 4; ++i)
#pragma unroll
        for (int j = 0; j < 4; ++j)
          acc[i][j] = __builtin_amdgcn_mfma_f32_16x16x32_f16(af[i], bfr[j], acc[i][j], 0, 0, 0);
    }
  }

  long coff = (long)kc * 2097152 + (long)b * 524288;
#pragma unroll
  for (int i = 0; i < 4; ++i)
#pragma unroll
    for (int j = 0; j < 4; ++j)
#pragma unroll
      for (int rr = 0; rr < 4; ++rr) {
        int row = m0 + wm + i * 16 + rq * 4 + rr;
        int col = n0 + wn + j * 16 + rl;
        Opart[coff + (long)row * 512 + col] = acc[i][j][rr];
      }
}

// L6: out[i] = sum_kc Opart[kc][i]. 2M floats, float4 per thread.
__global__ __launch_bounds__(256) void k_reduce(const float* __restrict__ Opart,
                                                float* __restrict__ out) {
  int i = blockIdx.x * 256 + threadIdx.x;
  float4 a = reinterpret_cast<const float4*>(Opart)[i];
  float4 b = reinterpret_cast<const float4*>(Opart + 2097152)[i];
  float4 c = reinterpret_cast<const float4*>(Opart + 4194304)[i];
  float4 d = reinterpret_cast<const float4*>(Opart + 6291456)[i];
  float4 o;
  o.x = (a.x + b.x) + (c.x + d.x);
  o.y = (a.y + b.y) + (c.y + d.y);
  o.z = (a.z + b.z) + (c.z + d.z);
  o.w = (a.w + b.w) + (c.w + d.w);
  reinterpret_cast<float4*>(out)[i] = o;
}

__global__ void k_sentinel(float* out, float v) { out[0] = v; }

extern "C" void kernel_launch(void* const* d_in, const int* in_sizes, int n_in,
                              void* d_out, int out_size, void* d_ws, size_t ws_size,
                              hipStream_t stream) {
  // setup_inputs dict order: x, Wk, Wq, Wv, Wu
  const float* x  = (const float*)d_in[0];
  const float* Wk = (const float*)d_in[1];
  const float* Wq = (const float*)d_in[2];
  const float* Wv = (const float*)d_in[3];
  const float* Wu = (const float*)d_in[4];
  float* out = (float*)d_out;

  const long SZ_X = 4096L * 512;
  const size_t NEED = 150994944;  // 144 MiB (we use 142)

  if (ws_size < NEED) {
    hipMemsetAsync(d_out, 0, (size_t)out_size * 4, stream);
    k_sentinel<<<1, 1, 0, stream>>>(out, (float)ws_size);
    return;
  }

  char* p = (char*)d_ws;
  unsigned short* Xbf  = (unsigned short*)p; p += SZ_X * 2;           //  4 MiB
  unsigned short* Wvut = (unsigned short*)p; p += 8L * 512 * 512 * 2; //  4 MiB [h][e][k]
  unsigned short* Gt   = (unsigned short*)p; p += 8L * 512 * 512 * 2; //  4 MiB [h][b'][a]
  unsigned short* T    = (unsigned short*)p; p += 4096L * 4096 * 2;   // 32 MiB [bt][h*512+b']
  unsigned short* Pb   = (unsigned short*)p; p += 4096L * 8192 * 2;   // 64 MiB [b][i][h*1024+j]
  unsigned short* VUt  = (unsigned short*)p; p += 4096L * 4096 * 2;   // 32 MiB [h*512+e][b*1024+j]
  float2* Stats = (float2*)p;                                          //  2 MiB [b][h][i][seg8]
  float* Opart = (float*)T;  // 32 MiB alias: T dead after S-gemm; 4x[4096][512] fp32

  // L1: x convert + weight folds (fp32-direct staging), one launch
  k_wsetup<<<dim3(8, 288), 256, 0, stream>>>(x, Wq, Wk, Wv, Wu, Xbf, Gt, Wvut);

  // L2: T = X.Gt^T (17.2 GF) + VU^T = Wvut.X^T (17.2 GF), fused
  k_gemm_tv<<<dim3(8, 256), 256, 0, stream>>>(Xbf, Gt, Wvut, T, VUt);

  // L3: P~ = exp(T.X^T - m_local) + stats (softmax fold, no separate pass)
  k_gemm_s<<<dim3(8, 256), 256, 0, stream>>>(Xbf, T, Pb, Stats);

  // L5: out partials = softmax(P) . VU^T, rescale fused into A-staging
  k_gemm_out<<<dim3(8, 64), 256, 0, stream>>>(Pb, VUt, Stats, Opart);

  // L6: out = sum of 4 partials
  k_reduce<<<2048, 256, 0, stream>>>(Opart, out);
}

// Round 3
// 250.748 us; speedup vs baseline: 1.0454x; 1.0046x over previous
//
#include <hip/hip_runtime.h>
#include <stdint.h>

typedef _Float16 f16x8 __attribute__((ext_vector_type(8)));
typedef float f32x4 __attribute__((ext_vector_type(4)));

__device__ __forceinline__ unsigned short f2h(float f) {
  _Float16 h = (_Float16)f;
  return __builtin_bit_cast(unsigned short, h);
}

#if __has_builtin(__builtin_amdgcn_global_load_lds)
#define HAVE_GLL 1
__device__ __forceinline__ void gload_lds16(const void* g, void* l) {
  auto gp = reinterpret_cast<const __attribute__((address_space(1))) void*>(
      reinterpret_cast<uintptr_t>(g));
  auto lp = reinterpret_cast<__attribute__((address_space(3))) void*>(
      reinterpret_cast<uintptr_t>(l));
  __builtin_amdgcn_global_load_lds(gp, lp, 16, 0, 0);
}
#else
#define HAVE_GLL 0
#endif

// ---------------- GEMM core: C[M,N] = A[M,K] * B[N,K]^T (fp16 inputs) ----------------
// 128x128 tile, BK=64, 256 threads (4 waves, 2x2 of 64x64), mfma 16x16x32 f16.
// LDS XOR-swizzled at 16B granularity; staging via global_load_lds(16B).
// PROVEN structure. R1's 8-phase 256^2 port REGRESSED (custom derived-waits !=
// m201 template); R2's fused-softmax epilogue REGRESSED (+15us VALU burst at
// kernel end, nothing to overlap). Both reverted — this is R0 verbatim except
// __launch_bounds__ min-waves 2->4 on the callers (see kernel comments).
// OUT: 0 fp32 store, 1 fp16 store. BVU: B rows live in VUt[h*512+e][b*1024+j].
template <int OUT, int BVU>
__device__ __forceinline__ void gemm_core(unsigned short* __restrict__ As,
                                          unsigned short* __restrict__ Bs,
                                          const unsigned short* __restrict__ A,
                                          const unsigned short* __restrict__ B,
                                          void* __restrict__ Cv, int K, int lda, int ldb,
                                          int ldc, long coff, int m0, int n0, int kbase) {
  int tid = threadIdx.x;
  int wid = tid >> 6, lane = tid & 63;
  int wm = (wid >> 1) * 64, wn = (wid & 1) * 64;
  int rq = lane >> 4, rl = lane & 15;

  f32x4 acc[4][4];
#pragma unroll
  for (int i = 0; i < 4; ++i)
#pragma unroll
    for (int j = 0; j < 4; ++j) acc[i][j] = (f32x4){0.f, 0.f, 0.f, 0.f};

#if HAVE_GLL
  int cg = (lane & 7) ^ ((lane >> 3) & 7);  // permuted global chunk -> swizzled LDS
  int rl8 = lane >> 3;                      // row within 8-row group
#endif

  for (int k0 = 0; k0 < K; k0 += 64) {
    long bko;
    if (BVU) {
      int kk = kbase + k0;
      bko = (long)(kk >> 10) * 2097152 + (kk & 1023);
    } else {
      bko = k0;
    }
    __syncthreads();
#if HAVE_GLL
#pragma unroll
    for (int t = 0; t < 4; ++t) {
      int r = wid * 32 + t * 8;  // uniform slab base row
      gload_lds16(&A[(long)(m0 + r + rl8) * lda + k0 + cg * 8], &As[r * 64]);
      gload_lds16(&B[(long)(n0 + r + rl8) * ldb + bko + cg * 8], &Bs[r * 64]);
    }
#else
#pragma unroll
    for (int it = 0; it < 4; ++it) {
      int idx = tid + it * 256;
      int r = idx >> 3, c = idx & 7;
      int cs = c ^ (r & 7);
      *reinterpret_cast<uint4*>(&As[r * 64 + cs * 8]) =
          *reinterpret_cast<const uint4*>(&A[(long)(m0 + r) * lda + k0 + c * 8]);
      *reinterpret_cast<uint4*>(&Bs[r * 64 + cs * 8]) =
          *reinterpret_cast<const uint4*>(&B[(long)(n0 + r) * ldb + bko + c * 8]);
    }
#endif
    __syncthreads();
#pragma unroll
    for (int ks = 0; ks < 2; ++ks) {
      f16x8 af[4], bfr[4];
      int kc = ks * 4 + rq;
#pragma unroll
      for (int i = 0; i < 4; ++i) {
        int ra = wm + i * 16 + rl;
        af[i] = *reinterpret_cast<const f16x8*>(&As[ra * 64 + ((kc ^ (ra & 7)) << 3)]);
        int rb = wn + i * 16 + rl;
        bfr[i] = *reinterpret_cast<const f16x8*>(&Bs[rb * 64 + ((kc ^ (rb & 7)) << 3)]);
      }
#pragma unroll
      for (int i = 0; i < 4; ++i)
#pragma unroll
        for (int j = 0; j < 4; ++j)
          acc[i][j] = __builtin_amdgcn_mfma_f32_16x16x32_f16(af[i], bfr[j], acc[i][j], 0, 0, 0);
    }
  }

#pragma unroll
  for (int i = 0; i < 4; ++i)
#pragma unroll
    for (int j = 0; j < 4; ++j)
#pragma unroll
      for (int r = 0; r < 4; ++r) {
        int row = m0 + wm + i * 16 + rq * 4 + r;
        int col = n0 + wn + j * 16 + rl;
        float v = acc[i][j][r];
        if (OUT == 1)
          reinterpret_cast<unsigned short*>(Cv)[coff + (long)row * ldc + col] = f2h(v);
        else
          reinterpret_cast<float*>(Cv)[coff + (long)row * ldc + col] = v;
      }
}

// ---------------- w_core: same 128x128xBK64 gemm but staging from RAW fp32 ----------------
// Only the tiny weight-fold launch uses this core — 256 gemm blocks, grid-limited
// to ~1 block/CU, perf non-critical.
__device__ __forceinline__ void w_core(unsigned short* __restrict__ As,
                                       unsigned short* __restrict__ Bs,
                                       const float* __restrict__ A32,
                                       const float* __restrict__ B32,
                                       unsigned short* __restrict__ C,
                                       int lda, int ldb, bool atrans, int m0, int n0) {
  int tid = threadIdx.x;
  int wid = tid >> 6, lane = tid & 63;
  int wm = (wid >> 1) * 64, wn = (wid & 1) * 64;
  int rq = lane >> 4, rl = lane & 15;

  f32x4 acc[4][4];
#pragma unroll
  for (int i = 0; i < 4; ++i)
#pragma unroll
    for (int j = 0; j < 4; ++j) acc[i][j] = (f32x4){0.f, 0.f, 0.f, 0.f};

  for (int k0 = 0; k0 < 512; k0 += 64) {
    __syncthreads();
    if (!atrans) {
#pragma unroll
      for (int it = 0; it < 8; ++it) {
        int idx = it * 256 + tid;
        int r = idx >> 4, kq = idx & 15;
        float4 v = *reinterpret_cast<const float4*>(&A32[(long)(m0 + r) * lda + k0 + kq * 4]);
        ushort4 u;
        u.x = f2h(v.x); u.y = f2h(v.y); u.z = f2h(v.z); u.w = f2h(v.w);
        int cs = (kq >> 1) ^ (r & 7);
        *reinterpret_cast<ushort4*>(&As[r * 64 + cs * 8 + (kq & 1) * 4]) = u;
      }
    } else {
#pragma unroll
      for (int it = 0; it < 32; ++it) {
        int idx = it * 256 + tid;
        int m = idx & 127, d = idx >> 7;  // coalesced over m (128x4B runs)
        float v = A32[(long)(k0 + d) * 512 + m0 + m];
        int cs = (d >> 3) ^ (m & 7);
        As[m * 64 + cs * 8 + (d & 7)] = f2h(v);
      }
    }
#pragma unroll
    for (int it = 0; it < 8; ++it) {
      int idx = it * 256 + tid;
      int r = idx >> 4, kq = idx & 15;
      float4 v = *reinterpret_cast<const float4*>(&B32[(long)(n0 + r) * ldb + k0 + kq * 4]);
      ushort4 u;
      u.x = f2h(v.x); u.y = f2h(v.y); u.z = f2h(v.z); u.w = f2h(v.w);
      int cs = (kq >> 1) ^ (r & 7);
      *reinterpret_cast<ushort4*>(&Bs[r * 64 + cs * 8 + (kq & 1) * 4]) = u;
    }
    __syncthreads();
#pragma unroll
    for (int ks = 0; ks < 2; ++ks) {
      f16x8 af[4], bfr[4];
      int kc = ks * 4 + rq;
#pragma unroll
      for (int i = 0; i < 4; ++i) {
        int ra = wm + i * 16 + rl;
        af[i] = *reinterpret_cast<const f16x8*>(&As[ra * 64 + ((kc ^ (ra & 7)) << 3)]);
        int rb = wn + i * 16 + rl;
        bfr[i] = *reinterpret_cast<const f16x8*>(&Bs[rb * 64 + ((kc ^ (rb & 7)) << 3)]);
      }
#pragma unroll
      for (int i = 0; i < 4; ++i)
#pragma unroll
        for (int j = 0; j < 4; ++j)
          acc[i][j] = __builtin_amdgcn_mfma_f32_16x16x32_f16(af[i], bfr[j], acc[i][j], 0, 0, 0);
    }
  }

#pragma unroll
  for (int i = 0; i < 4; ++i)
#pragma unroll
    for (int j = 0; j < 4; ++j)
#pragma unroll
      for (int r = 0; r < 4; ++r) {
        int row = m0 + wm + i * 16 + rq * 4 + r;
        int col = n0 + wn + j * 16 + rl;
        C[(long)row * 512 + col] = f2h(acc[i][j][r]);
      }
}

#define DECL_LDS \
  __shared__ unsigned short As[128 * 64]; \
  __shared__ unsigned short Bs[128 * 64];

// L1 (setup+folds merged, 7->6 nodes): grid (8, 288).
// w>=32: convert x fp32->fp16, block bi=(w-32)*8+c of 2048 (independent work).
// w<16 : Gt_h[b'][a] = sum_d Wq[b', h*512+d]*Wk[a, h*512+d], h=c, fp32-staged.
// w in [16,32): Wvut_h[e][k] = sum_d Wu[h*512+d, e]*Wv[k, h*512+d], A transposed.
// Stays (256,2): fp32 staging path has more live regs; fold blocks are
// grid-limited to 1/CU anyway, so the cap would risk spills for no gain.
__global__ __launch_bounds__(256, 2) void k_wsetup(
    const float* __restrict__ x, const float* __restrict__ Wq, const float* __restrict__ Wk,
    const float* __restrict__ Wv, const float* __restrict__ Wu,
    unsigned short* __restrict__ Xh, unsigned short* __restrict__ Gt,
    unsigned short* __restrict__ Wvut) {
  DECL_LDS
  int c = blockIdx.x, w = blockIdx.y;
  if (w >= 32) {
    int i = ((w - 32) * 8 + c) * 256 + threadIdx.x;
    float4 v = reinterpret_cast<const float4*>(x)[i];
    ushort4 u;
    u.x = f2h(v.x); u.y = f2h(v.y); u.z = f2h(v.z); u.w = f2h(v.w);
    reinterpret_cast<ushort4*>(Xh)[i] = u;
    return;
  }
  const float *A32, *B32;
  unsigned short* C;
  int lda;
  bool atrans;
  int t;
  if (w < 16) {
    A32 = Wq + c * 512; B32 = Wk + c * 512; C = Gt + (long)c * 262144;
    lda = 4096; atrans = false; t = w;
  } else {
    A32 = Wu + (long)c * 262144; B32 = Wv + c * 512; C = Wvut + (long)c * 262144;
    lda = 512; atrans = true; t = w - 16;
  }
  w_core(As, Bs, A32, B32, C, lda, 4096, atrans, (t >> 2) * 128, (t & 3) * 128);
}

// L2: T + VU projections fused, grid (8,256). ONE gemm_core<1,0> call.
// w<128 : T[bt][h*512+b'] = sum_a X[bt,a] * Gt_h[b',a]; h = c (XCD-pinned).
// w>=128: VUt[h*512+e][b*1024+j] = sum_k Wvut_h[e,k] * X[b*1024+j,k].
// (256,4): usage is 64 VGPR + 64 acc AGPR = 128 unified regs; cap forces the
// allocator to stay <=128 -> 4 blocks/CU (LDS 4x32K=128K <= 160K). At (256,2)
// measured occupancy ~29% (=2 blocks/CU): stray regs pushed us into the
// 256-reg class. 4 independent blocks/CU absorb each other's barrier drain
// (m114 mechanism) — the structure's ~20% stall.
__global__ __launch_bounds__(256, 4) void k_gemm_tv(
    const unsigned short* __restrict__ X, const unsigned short* __restrict__ Gt,
    const unsigned short* __restrict__ Wvut, unsigned short* __restrict__ T,
    unsigned short* __restrict__ VUt) {
  DECL_LDS
  int c = blockIdx.x, w = blockIdx.y;
  const unsigned short *A, *B;
  unsigned short* C;
  long coff;
  int m0, n0;
  if (w < 128) {
    A = X; B = Gt + (long)c * 262144; C = T;
    coff = (long)c * 512; m0 = (w >> 2) * 128; n0 = (w & 3) * 128;
  } else {
    int wp = w - 128;
    A = Wvut; B = X; C = VUt;
    coff = 0; m0 = (4 * c + (wp & 3)) * 128; n0 = (wp >> 2) * 128;
  }
  gemm_core<1, 0>(As, Bs, A, B, C, 512, 512, 512, 4096, coff, m0, n0, 0);
}

// L3: S-gemm, grid (8,256). z = c + 8*(w>>6) -> (b,h) pinned to XCD h.
// P[b][i][h*1024+j] = sum_b' T[b*1024+i, h*512+b'] * X[b*1024+j, b'].
__global__ __launch_bounds__(256, 4) void k_gemm_s(
    const unsigned short* __restrict__ X, const unsigned short* __restrict__ T,
    unsigned short* __restrict__ Pb) {
  DECL_LDS
  int c = blockIdx.x, w = blockIdx.y;
  int z = c + 8 * (w >> 6), t = w & 63;
  int b = z >> 3, h = z & 7;
  gemm_core<1, 0>(As, Bs, T + (long)b * 4194304 + h * 512, X + (long)b * 524288, Pb,
                  512, 4096, 512, 8192, (long)b * 8388608 + h * 1024,
                  (t >> 3) * 128, (t & 7) * 128, 0);
}

// L5: O-partials: Opart[kc][b*1024+i][e] = sum_{kk in chunk} Pb[b][i][kk] *
// VUt[(kk>>10)*512+e][b*1024+(kk&1023)]. grid (8,64), plain fp32 stores.
// Group g=(b,kchunk,ihalf): P slab 2 MiB + VU slab 2 MiB = one XCD L2.
__global__ __launch_bounds__(256, 4) void k_gemm_out(
    const unsigned short* __restrict__ Pb, const unsigned short* __restrict__ VUt,
    float* __restrict__ Opart) {
  DECL_LDS
  int c = blockIdx.x, w = blockIdx.y;
  int g = c + 8 * (w >> 4);  // 0..31
  int r = w & 15;
  int b = g >> 3, kc = (g >> 1) & 3, ih = g & 1;
  int y = ih * 4 + (r >> 2);  // 0..7  (i-tile)
  int x = r & 3;              // 0..3  (e-tile)
  gemm_core<0, 1>(As, Bs, Pb + (long)b * 8388608 + kc * 2048, VUt + (long)b * 1024,
                  Opart, 2048, 8192, 4096, 512,
                  (long)kc * 2097152 + (long)b * 524288, y * 128, x * 128, kc * 2048);
}

// L6: out[i] = sum_kc Opart[kc][i]. 2M floats, float4 per thread.
__global__ __launch_bounds__(256) void k_reduce(const float* __restrict__ Opart,
                                                float* __restrict__ out) {
  int i = blockIdx.x * 256 + threadIdx.x;
  float4 a = reinterpret_cast<const float4*>(Opart)[i];
  float4 b = reinterpret_cast<const float4*>(Opart + 2097152)[i];
  float4 c = reinterpret_cast<const float4*>(Opart + 4194304)[i];
  float4 d = reinterpret_cast<const float4*>(Opart + 6291456)[i];
  float4 o;
  o.x = (a.x + b.x) + (c.x + d.x);
  o.y = (a.y + b.y) + (c.y + d.y);
  o.z = (a.z + b.z) + (c.z + d.z);
  o.w = (a.w + b.w) + (c.w + d.w);
  reinterpret_cast<float4*>(out)[i] = o;
}

// L4: softmax, one wave per 1024-chunk of P[b][i][h*1024+j], in place.
// grid (8,1024): h = blockIdx.x (XCD-aligned with the S-gemm writer).
__global__ __launch_bounds__(256) void k_softmax_x(unsigned short* __restrict__ S) {
  int g = blockIdx.y * 4 + (threadIdx.x >> 6);
  int b = g >> 10, i = g & 1023;
  long base = (long)b * 8388608 + (long)i * 8192 + (long)blockIdx.x * 1024;
  int lane = threadIdx.x & 63;
  f16x8* p = reinterpret_cast<f16x8*>(S + base);
  f16x8 a = p[lane * 2], bb = p[lane * 2 + 1];
  float v[16];
#pragma unroll
  for (int q = 0; q < 8; ++q) { v[q] = (float)a[q]; v[8 + q] = (float)bb[q]; }
  float m = v[0];
#pragma unroll
  for (int q = 1; q < 16; ++q) m = fmaxf(m, v[q]);
#pragma unroll
  for (int o = 32; o; o >>= 1) m = fmaxf(m, __shfl_xor(m, o));
  float s = 0.f;
#pragma unroll
  for (int q = 0; q < 16; ++q) { v[q] = __expf(v[q] - m); s += v[q]; }
#pragma unroll
  for (int o = 32; o; o >>= 1) s += __shfl_xor(s, o);
  float inv = 1.0f / s;
  f16x8 oa, ob;
#pragma unroll
  for (int q = 0; q < 8; ++q) {
    oa[q] = (_Float16)(v[q] * inv);
    ob[q] = (_Float16)(v[8 + q] * inv);
  }
  p[lane * 2] = oa;
  p[lane * 2 + 1] = ob;
}

__global__ void k_sentinel(float* out, float v) { out[0] = v; }

extern "C" void kernel_launch(void* const* d_in, const int* in_sizes, int n_in,
                              void* d_out, int out_size, void* d_ws, size_t ws_size,
                              hipStream_t stream) {
  // setup_inputs dict order: x, Wk, Wq, Wv, Wu
  const float* x  = (const float*)d_in[0];
  const float* Wk = (const float*)d_in[1];
  const float* Wq = (const float*)d_in[2];
  const float* Wv = (const float*)d_in[3];
  const float* Wu = (const float*)d_in[4];
  float* out = (float*)d_out;

  const long SZ_X = 4096L * 512;
  const size_t NEED = 150994944;  // 144 MiB (we use 140; 180 verified previously)

  if (ws_size < NEED) {
    hipMemsetAsync(d_out, 0, (size_t)out_size * 4, stream);
    k_sentinel<<<1, 1, 0, stream>>>(out, (float)ws_size);
    return;
  }

  char* p = (char*)d_ws;
  unsigned short* Xbf  = (unsigned short*)p; p += SZ_X * 2;           //  4 MiB
  unsigned short* Wvut = (unsigned short*)p; p += 8L * 512 * 512 * 2; //  4 MiB [h][e][k]
  unsigned short* Gt   = (unsigned short*)p; p += 8L * 512 * 512 * 2; //  4 MiB [h][b'][a]
  unsigned short* T    = (unsigned short*)p; p += 4096L * 4096 * 2;   // 32 MiB [bt][h*512+b']
  unsigned short* Pb   = (unsigned short*)p; p += 4096L * 8192 * 2;   // 64 MiB [b][i][h*1024+j]
  unsigned short* VUt  = (unsigned short*)p;                          // 32 MiB [h*512+e][b*1024+j]
  float* Opart = (float*)T;  // 32 MiB alias: T dead after S-gemm; 4x[4096][512] fp32

  // L1: x convert + weight folds (fp32-direct staging), one launch
  k_wsetup<<<dim3(8, 288), 256, 0, stream>>>(x, Wq, Wk, Wv, Wu, Xbf, Gt, Wvut);

  // L2: T = X.Gt^T (17.2 GF) + VU^T = Wvut.X^T (17.2 GF), fused
  k_gemm_tv<<<dim3(8, 256), 256, 0, stream>>>(Xbf, Gt, Wvut, T, VUt);

  // L3: P[b][i][h*1024+j] = T.X^T (34.4 GF), B-operand = X (L2-tiny)
  k_gemm_s<<<dim3(8, 256), 256, 0, stream>>>(Xbf, T, Pb);

  // L4: softmax over each 1024-chunk of P, in place
  k_softmax_x<<<dim3(8, 1024), 256, 0, stream>>>(Pb);

  // L5: out partials = P . VU^T (strided-head B), plain fp32 stores
  k_gemm_out<<<dim3(8, 64), 256, 0, stream>>>(Pb, VUt, Opart);

  // L6: out = sum of 4 partials
  k_reduce<<<2048, 256, 0, stream>>>(Opart, out);
}